// Round 13
// baseline (171.349 us; speedup 1.0000x reference)
//
#include <hip/hip_runtime.h>

// B=4, S=2048, D=768, H=12, E=64, M=B*S=8192, N_qkv=2304
// scale = log2(e)/sqrt(S) folded into Q at QKV-GEMM epilogue (softmax via exp2).

typedef __bf16 bf16x8 __attribute__((ext_vector_type(8)));
typedef __bf16 bf16x4 __attribute__((ext_vector_type(4)));
typedef float  f32x4  __attribute__((ext_vector_type(4)));
typedef float  f32x16 __attribute__((ext_vector_type(16)));
typedef unsigned u32x4 __attribute__((ext_vector_type(4)));

#define MFMA16(a,b,c) __builtin_amdgcn_mfma_f32_16x16x32_bf16((a),(b),(c),0,0,0)
#define MFMA32(a,b,c) __builtin_amdgcn_mfma_f32_32x32x16_bf16((a),(b),(c),0,0,0)
// 1/sqrt(2048) * log2(e): scores land in log2 domain -> exp2 only, no mul.
#define QSCALE2 (0.022097086912079612f * 1.4426950408889634f)

__device__ __forceinline__ void gload16(const void* g, void* l) {
  __builtin_amdgcn_global_load_lds((const __attribute__((address_space(1))) void*)g,
                                   (__attribute__((address_space(3))) void*)l, 16, 0, 0);
}

// ---------------- pack: fp32 -> bf16 (+ weight transposes) ----------------
__global__ __launch_bounds__(256) void pack_kernel(
    const float* __restrict__ x, const float* __restrict__ Wq,
    const float* __restrict__ Wk, const float* __restrict__ Wv,
    const float* __restrict__ Wo,
    __bf16* __restrict__ xb, __bf16* __restrict__ wqkv, __bf16* __restrict__ wot) {
  int tid = blockIdx.x * 256 + threadIdx.x;
  int nth = gridDim.x * 256;
  for (int i = tid; i < 8192 * 768 / 4; i += nth) {
    float4 v = ((const float4*)x)[i];
    bf16x4 o; o[0] = (__bf16)v.x; o[1] = (__bf16)v.y; o[2] = (__bf16)v.z; o[3] = (__bf16)v.w;
    ((bf16x4*)xb)[i] = o;
  }
  for (int i = tid; i < 3 * 768 * 768; i += nth) {
    int n = i / 768, d = i - n * 768;
    int p = n / 768;
    int wn = n - p * 768;
    int h = wn >> 6, e = wn & 63;
    const float* W = (p == 0) ? Wq : (p == 1) ? Wk : Wv;
    wqkv[i] = (__bf16)W[(h * 768 + d) * 64 + e];
  }
  for (int i = tid; i < 768 * 768; i += nth) {
    int n = i / 768, k = i - n * 768;
    wot[i] = (__bf16)Wo[k * 768 + n];
  }
}

// -- GEMM core v13: 128x128 tile, BK=64, DOUBLE-BUFFERED, 12 steps x 1 barrier -
// v12 (BK=64 single-buf, 2 barriers/step, exposed load latency) cut gemm_qkv
// below 68us, confirming per-step overhead dominates. v13: regs (~156) cap at
// 2 blocks/CU regardless, so 64KB LDS dbuf is FREE. attn-proven shape: stage
// step t+1 at TOP of body t into the other buffer, compute this buffer, ONE
// barrier at end (drains prefetch after a full compute phase of cover).
// Barriers 24->12, load latency hidden. XOR swizzle kept: global src col
// pre-swizzled byte^=((row&7)<<4); read col XOR'd identically.
#define GEMM_STEP(B_, T_)                                                         \
  {                                                                               \
    if ((T_) < 11) {                                                              \
      const int kb_ = ((T_) + 1) * 128;                                           \
      _Pragma("unroll") for (int j = 0; j < 4; ++j) {                             \
        gload16(gA + j * 49152 + kb_, lA + ((B_) ^ 1) * 16384 + j * 4096);        \
        gload16(gB + j * 49152 + kb_, lB + ((B_) ^ 1) * 16384 + j * 4096);        \
      }                                                                           \
    }                                                                             \
    _Pragma("unroll") for (int kk = 0; kk < 2; ++kk) {                            \
      const int cx = kk ? colx1 : colx0;                                          \
      bf16x8 af[4], bfv[4];                                                       \
      _Pragma("unroll") for (int mt = 0; mt < 4; ++mt)                            \
        af[mt] = *(const bf16x8*)((char*)As + (B_) * 16384 +                      \
                                  (wr * 64 + mt * 16 + ln) * 128 + cx);           \
      _Pragma("unroll") for (int nt = 0; nt < 4; ++nt)                            \
        bfv[nt] = *(const bf16x8*)((char*)Bs + (B_) * 16384 +                     \
                                   (wc * 64 + nt * 16 + ln) * 128 + cx);          \
      _Pragma("unroll") for (int mt = 0; mt < 4; ++mt)                            \
        _Pragma("unroll") for (int nt = 0; nt < 4; ++nt)                          \
          acc[mt][nt] = MFMA16(af[mt], bfv[nt], acc[mt][nt]);                     \
    }                                                                             \
    __syncthreads();                                                              \
  }

#define GEMM_CORE(A_, Bt_, m0_, n0_)                                              \
  __shared__ __align__(16) __bf16 As[2][128 * 64];                                \
  __shared__ __align__(16) __bf16 Bs[2][128 * 64];                                \
  const int tid = threadIdx.x;                                                    \
  const int w = tid >> 6, lane = tid & 63, ln = lane & 15, hi = lane >> 4;        \
  const int wr = w >> 1, wc = w & 1;                                              \
  f32x4 acc[4][4];                                                                \
  {                                                                               \
    f32x4 z = {0.f, 0.f, 0.f, 0.f};                                               \
    _Pragma("unroll") for (int i = 0; i < 4; ++i)                                 \
      _Pragma("unroll") for (int j = 0; j < 4; ++j) acc[i][j] = z;                \
  }                                                                               \
  const int colx0 = ((hi) ^ (ln & 7)) << 4;      /* kk=0 read col (swizzled) */   \
  const int colx1 = ((4 + hi) ^ (ln & 7)) << 4;  /* kk=1 read col (swizzled) */   \
  {                                                                               \
    const int r0 = tid >> 3;                       /* staged row (per 32-group) */\
    const int scb = ((tid & 7) * 16) ^ ((r0 & 7) << 4);  /* pre-swizzled src */   \
    const char* gA = (const char*)(A_) + (size_t)(m0_ + r0) * 1536 + scb;         \
    const char* gB = (const char*)(Bt_) + (size_t)(n0_ + r0) * 1536 + scb;        \
    char* lA = (char*)As + w * 1024;   /* wave-uniform dest (lane*16 implicit) */ \
    char* lB = (char*)Bs + w * 1024;                                              \
    _Pragma("unroll") for (int j = 0; j < 4; ++j) {                               \
      gload16(gA + j * 49152, lA + j * 4096);                                     \
      gload16(gB + j * 49152, lB + j * 4096);                                     \
    }                                                                             \
    __syncthreads();                                                              \
    for (int kt = 0; kt < 12; kt += 2) {                                          \
      GEMM_STEP(0, kt)                                                            \
      GEMM_STEP(1, kt + 1)                                                        \
    }                                                                             \
  }

__global__ __launch_bounds__(256) void gemm_qkv(
    const __bf16* __restrict__ A, const __bf16* __restrict__ Bt,
    const float* __restrict__ bq, const float* __restrict__ bk,
    const float* __restrict__ bv,
    __bf16* __restrict__ qb, __bf16* __restrict__ kb, __bf16* __restrict__ vt) {
  // T1: XCD-aware bijective swizzle (nwg=1152, 144/XCD; consecutive swz share A-panels)
  const int lin = blockIdx.y * 18 + blockIdx.x;
  const int swzb = (lin & 7) * 144 + (lin >> 3);
  const int m0 = (swzb / 18) * 128, n0 = (swzb % 18) * 128;
  GEMM_CORE(A, Bt, m0, n0)
  const int p = n0 / 768;
  const float* bias = (p == 0) ? bq : (p == 1) ? bk : bv;
  const float sc = (p == 0) ? QSCALE2 : 1.0f;
#pragma unroll
  for (int nt = 0; nt < 4; ++nt) {
    int n = n0 + wc * 64 + nt * 16 + ln;
    int wn = n - p * 768;
    int h = wn >> 6, e = wn & 63;
    float bb = bias[wn];
#pragma unroll
    for (int mt = 0; mt < 4; ++mt) {
      int mrow = m0 + wr * 64 + mt * 16 + hi * 4;
      int b = mrow >> 11, s0 = mrow & 2047;
      if (p == 2) {
        bf16x4 pk;
#pragma unroll
        for (int r = 0; r < 4; ++r) pk[r] = (__bf16)(acc[mt][nt][r] + bb);
        *(bf16x4*)&vt[(((size_t)b * 12 + h) * 64 + e) * 2048 + s0] = pk;
      } else {
        __bf16* dst = (p == 0) ? qb : kb;
#pragma unroll
        for (int r = 0; r < 4; ++r)
          dst[(((size_t)b * 12 + h) * 2048 + s0 + r) * 64 + e] =
              (__bf16)((acc[mt][nt][r] + bb) * sc);
      }
    }
  }
}

// h stored bf16 (halves write), residual from xb (bf16, halves read).
__global__ __launch_bounds__(256) void gemm_proj(
    const __bf16* __restrict__ A, const __bf16* __restrict__ Bt,
    const float* __restrict__ bo, const __bf16* __restrict__ xres,
    __bf16* __restrict__ hout) {
  // T1 swizzle (nwg=384, 48/XCD)
  const int lin = blockIdx.y * 6 + blockIdx.x;
  const int swzb = (lin & 7) * 48 + (lin >> 3);
  const int m0 = (swzb / 6) * 128, n0 = (swzb % 6) * 128;
  GEMM_CORE(A, Bt, m0, n0)
#pragma unroll
  for (int nt = 0; nt < 4; ++nt) {
    int n = n0 + wc * 64 + nt * 16 + ln;
    float bb = bo[n];
#pragma unroll
    for (int mt = 0; mt < 4; ++mt) {
      int mrow = m0 + wr * 64 + mt * 16 + hi * 4;
#pragma unroll
      for (int r = 0; r < 4; ++r) {
        size_t idx = (size_t)(mrow + r) * 768 + n;
        hout[idx] = (__bf16)(acc[mt][nt][r] + bb + (float)xres[idx]);
      }
    }
  }
}

// ------- flash attention v13: KVBLK=128, dbuf 64KB LDS, 16 tiles/barriers ----
// Same proven per-64-row compute (swapped mfma(K,Q), in-reg P via cvt_pk +
// permlane32_swap, lsum via MFMA(P,ones), XOR-swizzled K/V) applied twice per
// tile at base + half*8192 -- zero register growth. Barrier count 32 -> 16;
// staged 32KB/tile has a full 2x compute phase (~3600cy) of latency cover.
// LDS 64KB -> 2 blocks/CU = what the 132-reg budget already limits us to.
__global__ __launch_bounds__(256) void attn_kernel(
    const __bf16* __restrict__ qb, const __bf16* __restrict__ kb,
    const __bf16* __restrict__ vt, __bf16* __restrict__ ctx) {
  // LDS: K dbuf [2][16KB] at 0, V^T dbuf [2][16KB] at 32768.
  __shared__ __align__(16) char lds[65536];
  const int tid = threadIdx.x;
  const int w = tid >> 6, lane = tid & 63;
  const int l31 = lane & 31, h = lane >> 5;
  const int bh = blockIdx.x;
  const int q0 = blockIdx.y * 128 + w * 32;

  // ---- staging: thread covers linear LDS bytes o=tid*16 (and +4096) per half
  const int o0 = tid * 16, o1 = o0 + 4096;
  const int r0s = o0 >> 7, cb0 = o0 & 127;
  const int r1s = o1 >> 7, cb1 = o1 & 127;
  const char* kgb = (const char*)(kb + (size_t)bh * 2048 * 64);
  const char* vgb = (const char*)(vt + (size_t)bh * 64 * 2048);
  const char* ksrc0 = kgb + r0s * 128 + (cb0 ^ ((r0s & 7) << 4));
  const char* ksrc1 = kgb + r1s * 128 + (cb1 ^ ((r1s & 7) << 4));
  const char* vsrc0 = vgb + r0s * 4096 + (cb0 ^ ((r0s & 7) << 4));
  const char* vsrc1 = vgb + r1s * 4096 + (cb1 ^ ((r1s & 7) << 4));
  char* kl0 = lds + w * 1024;            // wave-uniform LDS base (lane*16 implicit)
  char* vl0 = lds + 32768 + w * 1024;

  // tile t covers kv rows [t*128, t*128+128): K bytes t*16384 (+8192 half1),
  // V^T bytes t*256 (+128 half1, row stride 4096).
#define STAGE128(t_, b_) do {                                                  \
    char* kd_ = kl0 + (b_) * 16384;                                            \
    char* vd_ = vl0 + (b_) * 16384;                                            \
    gload16(ksrc0 + (size_t)(t_) * 16384,        kd_);                         \
    gload16(ksrc1 + (size_t)(t_) * 16384,        kd_ + 4096);                  \
    gload16(ksrc0 + (size_t)(t_) * 16384 + 8192, kd_ + 8192);                  \
    gload16(ksrc1 + (size_t)(t_) * 16384 + 8192, kd_ + 12288);                 \
    gload16(vsrc0 + (size_t)(t_) * 256,          vd_);                         \
    gload16(vsrc1 + (size_t)(t_) * 256,          vd_ + 4096);                  \
    gload16(vsrc0 + (size_t)(t_) * 256 + 128,    vd_ + 8192);                  \
    gload16(vsrc1 + (size_t)(t_) * 256 + 128,    vd_ + 12288);                 \
  } while (0)

  // ---- Q fragments (B-operand of mfma(K,Q)): col=q=l31, k(e)=16s+8h+j
  const __bf16* qp = qb + ((size_t)bh * 2048 + q0 + l31) * 64 + h * 8;
  bf16x8 qf[4];
#pragma unroll
  for (int s = 0; s < 4; ++s) qf[s] = *(const bf16x8*)(qp + 16 * s);

  // ---- per-lane swizzled LDS read addresses, relative to a half-tile base
  const int swz = (l31 & 7) << 4;
  const int krd = l31 * 128 + ((h * 16) ^ swz);
  int ka_[8], va_[8];
#pragma unroll
  for (int kvt = 0; kvt < 2; ++kvt)
#pragma unroll
    for (int s = 0; s < 4; ++s) ka_[kvt * 4 + s] = (krd + kvt * 4096) ^ (s * 32);
#pragma unroll
  for (int ks = 0; ks < 4; ++ks)
#pragma unroll
    for (int et = 0; et < 2; ++et) va_[ks * 2 + et] = (krd + et * 4096) ^ (ks * 32);

  // ---- loop-invariant constants: zero C-init, ones B-frag for lsum-MFMA
  f32x16 FZ;
#pragma unroll
  for (int r = 0; r < 16; ++r) FZ[r] = 0.f;
  bf16x8 onesf;
#pragma unroll
  for (int j = 0; j < 8; ++j) onesf[j] = (__bf16)1.0f;

  f32x16 lacc = FZ;
  f32x16 cacc[2];
  cacc[0] = FZ; cacc[1] = FZ;

  STAGE128(0, 0);
  __syncthreads();

#define PKPAIR(dst_, i_)                                                       \
  {                                                                            \
    float pa_ = __builtin_amdgcn_exp2f(sa[2 * (i_)]);                          \
    float pb_ = __builtin_amdgcn_exp2f(sa[2 * (i_) + 1]);                      \
    asm("v_cvt_pk_bf16_f32 %0, %1, %2" : "=v"(dst_) : "v"(pa_), "v"(pb_));     \
  }

#define TILEHALF(KB_, VB_)                                                     \
  {                                                                            \
    const char* kb_l = (KB_);                                                  \
    const char* vb_l = (VB_);                                                  \
    bf16x8 kf[2][4], vf[4][2];                                                 \
    _Pragma("unroll") for (int kvt = 0; kvt < 2; ++kvt)                        \
      _Pragma("unroll") for (int s = 0; s < 4; ++s)                            \
        kf[kvt][s] = *(const bf16x8*)(kb_l + ka_[kvt * 4 + s]);                \
    _Pragma("unroll") for (int ks = 0; ks < 4; ++ks)                           \
      _Pragma("unroll") for (int et = 0; et < 2; ++et)                         \
        vf[ks][et] = *(const bf16x8*)(vb_l + va_[ks * 2 + et]);                \
    u32x4 pau[4];                                                              \
    _Pragma("unroll") for (int kvt = 0; kvt < 2; ++kvt) {                      \
      __builtin_amdgcn_s_setprio(1);                                           \
      f32x16 sa = MFMA32(kf[kvt][0], qf[0], FZ);                               \
      sa = MFMA32(kf[kvt][1], qf[1], sa);                                      \
      sa = MFMA32(kf[kvt][2], qf[2], sa);                                      \
      sa = MFMA32(kf[kvt][3], qf[3], sa);                                      \
      __builtin_amdgcn_s_setprio(0);                                           \
      unsigned c0, c1, c2, c3, c4, c5, c6, c7;                                 \
      PKPAIR(c0, 0) PKPAIR(c1, 1) PKPAIR(c2, 2) PKPAIR(c3, 3)                  \
      PKPAIR(c4, 4) PKPAIR(c5, 5) PKPAIR(c6, 6) PKPAIR(c7, 7)                  \
      asm("v_permlane32_swap_b32 %0, %1" : "+v"(c0), "+v"(c2));                \
      asm("v_permlane32_swap_b32 %0, %1" : "+v"(c1), "+v"(c3));                \
      asm("v_permlane32_swap_b32 %0, %1" : "+v"(c4), "+v"(c6));                \
      asm("v_permlane32_swap_b32 %0, %1" : "+v"(c5), "+v"(c7));                \
      pau[2 * kvt][0] = c0; pau[2 * kvt][1] = c1;                              \
      pau[2 * kvt][2] = c2; pau[2 * kvt][3] = c3;                              \
      pau[2 * kvt + 1][0] = c4; pau[2 * kvt + 1][1] = c5;                      \
      pau[2 * kvt + 1][2] = c6; pau[2 * kvt + 1][3] = c7;                      \
      lacc = MFMA32(__builtin_bit_cast(bf16x8, pau[2 * kvt]), onesf, lacc);    \
      lacc = MFMA32(__builtin_bit_cast(bf16x8, pau[2 * kvt + 1]), onesf, lacc);\
    }                                                                          \
    __builtin_amdgcn_s_setprio(1);                                             \
    _Pragma("unroll") for (int ks = 0; ks < 4; ++ks) {                         \
      bf16x8 paf = __builtin_bit_cast(bf16x8, pau[ks]);                        \
      cacc[0] = MFMA32(paf, vf[ks][0], cacc[0]);                               \
      cacc[1] = MFMA32(paf, vf[ks][1], cacc[1]);                               \
    }                                                                          \
    __builtin_amdgcn_s_setprio(0);                                             \
  }

#define TILE128(B_, T_)                                                        \
  {                                                                            \
    if ((T_) < 15) STAGE128((T_) + 1, (B_) ^ 1);                               \
    TILEHALF(lds + (B_) * 16384,        lds + 32768 + (B_) * 16384)            \
    TILEHALF(lds + (B_) * 16384 + 8192, lds + 32768 + (B_) * 16384 + 8192)     \
    __syncthreads();                                                           \
  }

  for (int t = 0; t < 16; t += 2) {
    TILE128(0, t)
    TILE128(1, t + 1)
  }
#undef TILE128
#undef TILEHALF
#undef PKPAIR
#undef STAGE128

  // lacc[r] = full softmax denom for q-row ql(r,h) (same row map as cacc[*][r])
  const int b = bh / 12, hh = bh - b * 12;
#pragma unroll
  for (int r = 0; r < 16; ++r) {
    const int ql = (r & 3) + 8 * (r >> 2) + 4 * h;
    float rl = __builtin_amdgcn_rcpf(lacc[r]);
    size_t base = ((size_t)b * 2048 + q0 + ql) * 768 + hh * 64 + l31;
    ctx[base]      = (__bf16)(cacc[0][r] * rl);
    ctx[base + 32] = (__bf16)(cacc[1][r] * rl);
  }
}

// ---------------- LayerNorm over 768 (one row per block, bf16 h) ----------------
__global__ __launch_bounds__(256) void ln_kernel(
    const __bf16* __restrict__ hb, const float* __restrict__ gamma,
    const float* __restrict__ beta, float* __restrict__ out) {
  __shared__ float ssum[4], ssq[4];
  const int row = blockIdx.x, t = threadIdx.x;
  const __bf16* hr = hb + (size_t)row * 768;
  float v0 = (float)hr[t], v1 = (float)hr[t + 256], v2 = (float)hr[t + 512];
  float sum = v0 + v1 + v2;
  float sq = v0 * v0 + v1 * v1 + v2 * v2;
#pragma unroll
  for (int mask = 1; mask < 64; mask <<= 1) {
    sum += __shfl_xor(sum, mask, 64);
    sq += __shfl_xor(sq, mask, 64);
  }
  const int w = t >> 6;
  if ((t & 63) == 0) { ssum[w] = sum; ssq[w] = sq; }
  __syncthreads();
  float s1 = ssum[0] + ssum[1] + ssum[2] + ssum[3];
  float s2 = ssq[0] + ssq[1] + ssq[2] + ssq[3];
  float mu = s1 * (1.0f / 768.0f);
  float var = s2 * (1.0f / 768.0f) - mu * mu;
  float rs = rsqrtf(var + 1e-5f);
  float* orow = out + (size_t)row * 768;
  orow[t]       = (v0 - mu) * rs * gamma[t]       + beta[t];
  orow[t + 256] = (v1 - mu) * rs * gamma[t + 256] + beta[t + 256];
  orow[t + 512] = (v2 - mu) * rs * gamma[t + 512] + beta[t + 512];
}

// ---------------- launch ----------------
extern "C" void kernel_launch(void* const* d_in, const int* in_sizes, int n_in,
                              void* d_out, int out_size, void* d_ws, size_t ws_size,
                              hipStream_t stream) {
  const float* x     = (const float*)d_in[0];
  const float* Wq    = (const float*)d_in[1];
  const float* bq    = (const float*)d_in[2];
  const float* Wk    = (const float*)d_in[3];
  const float* bk    = (const float*)d_in[4];
  const float* Wv    = (const float*)d_in[5];
  const float* bv    = (const float*)d_in[6];
  const float* Wo    = (const float*)d_in[7];
  const float* bo    = (const float*)d_in[8];
  const float* gamma = (const float*)d_in[9];
  const float* beta  = (const float*)d_in[10];
  float* out = (float*)d_out;

  char* ws = (char*)d_ws;
  __bf16* xb   = (__bf16*)(ws);                 // 12582912
  __bf16* wqkv = (__bf16*)(ws + 12582912);      //  3538944
  __bf16* wot  = (__bf16*)(ws + 16121856);      //  1179648
  __bf16* qb   = (__bf16*)(ws + 17301504);      // 12582912
  __bf16* kb   = (__bf16*)(ws + 29884416);      // 12582912
  __bf16* vt   = (__bf16*)(ws + 42467328);      // 12582912
  __bf16* ctx  = (__bf16*)(ws + 55050240);      // 12582912
  __bf16* hb   = (__bf16*)(ws + 67633152);      // 12582912 (bf16)

  pack_kernel<<<dim3(1024), dim3(256), 0, stream>>>(x, Wq, Wk, Wv, Wo, xb, wqkv, wot);
  gemm_qkv<<<dim3(18, 64), dim3(256), 0, stream>>>(xb, wqkv, bq, bk, bv, qb, kb, vt);
  attn_kernel<<<dim3(48, 16), dim3(256), 0, stream>>>(qb, kb, vt, ctx);
  gemm_proj<<<dim3(6, 64), dim3(256), 0, stream>>>(ctx, wot, bo, xb, hb);
  ln_kernel<<<dim3(8192), dim3(256), 0, stream>>>(hb, gamma, beta, out);
}

// Round 14
// 158.196 us; speedup vs baseline: 1.0831x; 1.0831x over previous
//
#include <hip/hip_runtime.h>

// B=4, S=2048, D=768, H=12, E=64, M=B*S=8192, N_qkv=2304
// scale = log2(e)/sqrt(S) folded into Q at QKV-GEMM epilogue (softmax via exp2).
// ROUND-14 = exact restore of round-12 best (158.1us measured):
//   - gemm v12: BK=64 single-buffer (BK=64 was the one GEMM lever that moved;
//     dbuf/counted-vmcnt/small-tile all neutral-or-worse)
//   - attn r4-version: 32KB LDS, 3 blocks/CU (KVBLK=128@64KB cost occupancy)
//   - bf16 h + residual from xb (IO halving, absmax 0.031 < 0.099)

typedef __bf16 bf16x8 __attribute__((ext_vector_type(8)));
typedef __bf16 bf16x4 __attribute__((ext_vector_type(4)));
typedef float  f32x4  __attribute__((ext_vector_type(4)));
typedef float  f32x16 __attribute__((ext_vector_type(16)));
typedef unsigned u32x4 __attribute__((ext_vector_type(4)));

#define MFMA16(a,b,c) __builtin_amdgcn_mfma_f32_16x16x32_bf16((a),(b),(c),0,0,0)
#define MFMA32(a,b,c) __builtin_amdgcn_mfma_f32_32x32x16_bf16((a),(b),(c),0,0,0)
#define QSCALE2 (0.022097086912079612f * 1.4426950408889634f)

__device__ __forceinline__ void gload16(const void* g, void* l) {
  __builtin_amdgcn_global_load_lds((const __attribute__((address_space(1))) void*)g,
                                   (__attribute__((address_space(3))) void*)l, 16, 0, 0);
}

// ---------------- pack: fp32 -> bf16 (+ weight transposes) ----------------
__global__ __launch_bounds__(256) void pack_kernel(
    const float* __restrict__ x, const float* __restrict__ Wq,
    const float* __restrict__ Wk, const float* __restrict__ Wv,
    const float* __restrict__ Wo,
    __bf16* __restrict__ xb, __bf16* __restrict__ wqkv, __bf16* __restrict__ wot) {
  int tid = blockIdx.x * 256 + threadIdx.x;
  int nth = gridDim.x * 256;
  for (int i = tid; i < 8192 * 768 / 4; i += nth) {
    float4 v = ((const float4*)x)[i];
    bf16x4 o; o[0] = (__bf16)v.x; o[1] = (__bf16)v.y; o[2] = (__bf16)v.z; o[3] = (__bf16)v.w;
    ((bf16x4*)xb)[i] = o;
  }
  for (int i = tid; i < 3 * 768 * 768; i += nth) {
    int n = i / 768, d = i - n * 768;
    int p = n / 768;
    int wn = n - p * 768;
    int h = wn >> 6, e = wn & 63;
    const float* W = (p == 0) ? Wq : (p == 1) ? Wk : Wv;
    wqkv[i] = (__bf16)W[(h * 768 + d) * 64 + e];
  }
  for (int i = tid; i < 768 * 768; i += nth) {
    int n = i / 768, k = i - n * 768;
    wot[i] = (__bf16)Wo[k * 768 + n];
  }
}

// ---- GEMM core v12: 128x128 tile, BK=64, single buffer, 12 K-steps ----------
// Per-K-step fixed overhead (2 barriers + ds_read latency + issue serialization)
// dominates this short-K shape; BK=64 halves step count (24->12) = the one
// proven GEMM lever (r12: qkv ~69.5 -> <68, total -7.3us). LDS 32KB keeps
// 3 blocks/CU. 128B rows XOR-swizzled: LDS dest linear, global SOURCE
// pre-swizzled byte^=((row&7)<<4), read col XOR'd identically -> conflict-free.
#define GEMM_CORE(A_, Bt_, m0_, n0_)                                              \
  __shared__ __align__(16) __bf16 As[128 * 64];                                   \
  __shared__ __align__(16) __bf16 Bs[128 * 64];                                   \
  const int tid = threadIdx.x;                                                    \
  const int w = tid >> 6, lane = tid & 63, ln = lane & 15, hi = lane >> 4;        \
  const int wr = w >> 1, wc = w & 1;                                              \
  f32x4 acc[4][4];                                                                \
  {                                                                               \
    f32x4 z = {0.f, 0.f, 0.f, 0.f};                                               \
    _Pragma("unroll") for (int i = 0; i < 4; ++i)                                 \
      _Pragma("unroll") for (int j = 0; j < 4; ++j) acc[i][j] = z;                \
  }                                                                               \
  const int colx0 = ((hi) ^ (ln & 7)) << 4;      /* kk=0 read col (swizzled) */   \
  const int colx1 = ((4 + hi) ^ (ln & 7)) << 4;  /* kk=1 read col (swizzled) */   \
  {                                                                               \
    const int r0 = tid >> 3;                       /* staged row (per 32-group) */\
    const int scb = ((tid & 7) * 16) ^ ((r0 & 7) << 4);  /* pre-swizzled src */   \
    const char* gA = (const char*)(A_) + (size_t)(m0_ + r0) * 1536 + scb;         \
    const char* gB = (const char*)(Bt_) + (size_t)(n0_ + r0) * 1536 + scb;        \
    char* lA = (char*)As + w * 1024;   /* wave-uniform dest (lane*16 implicit) */ \
    char* lB = (char*)Bs + w * 1024;                                              \
    for (int kt = 0; kt < 12; ++kt) {                                             \
      const int kb = kt * 128;                                                    \
      _Pragma("unroll") for (int j = 0; j < 4; ++j) {                             \
        gload16(gA + j * 49152 + kb, lA + j * 4096);                              \
        gload16(gB + j * 49152 + kb, lB + j * 4096);                              \
      }                                                                           \
      __syncthreads();                                                            \
      _Pragma("unroll") for (int kk = 0; kk < 2; ++kk) {                          \
        const int cx = kk ? colx1 : colx0;                                        \
        bf16x8 af[4], bfv[4];                                                     \
        _Pragma("unroll") for (int mt = 0; mt < 4; ++mt)                          \
          af[mt] = *(const bf16x8*)((char*)As + (wr * 64 + mt * 16 + ln) * 128 + cx); \
        _Pragma("unroll") for (int nt = 0; nt < 4; ++nt)                          \
          bfv[nt] = *(const bf16x8*)((char*)Bs + (wc * 64 + nt * 16 + ln) * 128 + cx); \
        _Pragma("unroll") for (int mt = 0; mt < 4; ++mt)                          \
          _Pragma("unroll") for (int nt = 0; nt < 4; ++nt)                        \
            acc[mt][nt] = MFMA16(af[mt], bfv[nt], acc[mt][nt]);                   \
      }                                                                           \
      __syncthreads();                                                            \
    }                                                                             \
  }

__global__ __launch_bounds__(256) void gemm_qkv(
    const __bf16* __restrict__ A, const __bf16* __restrict__ Bt,
    const float* __restrict__ bq, const float* __restrict__ bk,
    const float* __restrict__ bv,
    __bf16* __restrict__ qb, __bf16* __restrict__ kb, __bf16* __restrict__ vt) {
  // T1: XCD-aware bijective swizzle (nwg=1152, 144/XCD)
  const int lin = blockIdx.y * 18 + blockIdx.x;
  const int swzb = (lin & 7) * 144 + (lin >> 3);
  const int m0 = (swzb / 18) * 128, n0 = (swzb % 18) * 128;
  GEMM_CORE(A, Bt, m0, n0)
  const int p = n0 / 768;
  const float* bias = (p == 0) ? bq : (p == 1) ? bk : bv;
  const float sc = (p == 0) ? QSCALE2 : 1.0f;
#pragma unroll
  for (int nt = 0; nt < 4; ++nt) {
    int n = n0 + wc * 64 + nt * 16 + ln;
    int wn = n - p * 768;
    int h = wn >> 6, e = wn & 63;
    float bb = bias[wn];
#pragma unroll
    for (int mt = 0; mt < 4; ++mt) {
      int mrow = m0 + wr * 64 + mt * 16 + hi * 4;
      int b = mrow >> 11, s0 = mrow & 2047;
      if (p == 2) {
        bf16x4 pk;
#pragma unroll
        for (int r = 0; r < 4; ++r) pk[r] = (__bf16)(acc[mt][nt][r] + bb);
        *(bf16x4*)&vt[(((size_t)b * 12 + h) * 64 + e) * 2048 + s0] = pk;
      } else {
        __bf16* dst = (p == 0) ? qb : kb;
#pragma unroll
        for (int r = 0; r < 4; ++r)
          dst[(((size_t)b * 12 + h) * 2048 + s0 + r) * 64 + e] =
              (__bf16)((acc[mt][nt][r] + bb) * sc);
      }
    }
  }
}

// h stored bf16 (halves write), residual from xb (bf16, halves read).
__global__ __launch_bounds__(256) void gemm_proj(
    const __bf16* __restrict__ A, const __bf16* __restrict__ Bt,
    const float* __restrict__ bo, const __bf16* __restrict__ xres,
    __bf16* __restrict__ hout) {
  // T1 swizzle (nwg=384, 48/XCD)
  const int lin = blockIdx.y * 6 + blockIdx.x;
  const int swzb = (lin & 7) * 48 + (lin >> 3);
  const int m0 = (swzb / 6) * 128, n0 = (swzb % 6) * 128;
  GEMM_CORE(A, Bt, m0, n0)
#pragma unroll
  for (int nt = 0; nt < 4; ++nt) {
    int n = n0 + wc * 64 + nt * 16 + ln;
    float bb = bo[n];
#pragma unroll
    for (int mt = 0; mt < 4; ++mt) {
      int mrow = m0 + wr * 64 + mt * 16 + hi * 4;
#pragma unroll
      for (int r = 0; r < 4; ++r) {
        size_t idx = (size_t)(mrow + r) * 768 + n;
        hout[idx] = (__bf16)(acc[mt][nt][r] + bb + (float)xres[idx]);
      }
    }
  }
}

// ---------------- flash attention: 32x32 MFMA, in-register P, swizzled LDS ----
// Best measured: 69us. grid (48,16): block = (b*12+h, 128 q). 4 waves x 32 q.
// KVBLK=64, dbuf 32KB LDS, 3 blocks/CU. Swapped mfma(K,Q): lane (q=lane&31,
// h=lane>>5) holds P[q][kv=(r&3)+8*(r>>2)+4h]; cvt_pk + permlane32_swap builds
// PV A-frags in-register; lsum via MFMA(P,ones). K/V XOR-swizzle
// byte^=((row&7)<<4) with pre-swizzled global source; ^32s col steps.
// Refuted: no-LDS (v5 186us), T15 (v6 spill), kv-split (v7 reg-capped),
// KVBLK=128 (v13 occupancy loss). XCD = bh%8 via identity blockIdx.
__global__ __launch_bounds__(256, 3) void attn_kernel(
    const __bf16* __restrict__ qb, const __bf16* __restrict__ kb,
    const __bf16* __restrict__ vt, __bf16* __restrict__ ctx) {
  __shared__ __align__(16) char lds[32768];
  const int tid = threadIdx.x;
  const int w = tid >> 6, lane = tid & 63;
  const int l31 = lane & 31, h = lane >> 5;
  const int bh = blockIdx.x;
  const int q0 = blockIdx.y * 128 + w * 32;

  const int o0 = tid * 16, o1 = o0 + 4096;
  const int r0s = o0 >> 7, cb0 = o0 & 127;
  const int r1s = o1 >> 7, cb1 = o1 & 127;
  const char* kgb = (const char*)(kb + (size_t)bh * 2048 * 64);
  const char* vgb = (const char*)(vt + (size_t)bh * 64 * 2048);
  const char* ksrc0 = kgb + r0s * 128 + (cb0 ^ ((r0s & 7) << 4));
  const char* ksrc1 = kgb + r1s * 128 + (cb1 ^ ((r1s & 7) << 4));
  const char* vsrc0 = vgb + r0s * 4096 + (cb0 ^ ((r0s & 7) << 4));
  const char* vsrc1 = vgb + r1s * 4096 + (cb1 ^ ((r1s & 7) << 4));
  char* kl0 = lds + w * 1024;
  char* vl0 = lds + 16384 + w * 1024;

#define STAGE(t_, b_) do {                                   \
    gload16(ksrc0 + (size_t)(t_) * 8192, kl0 + (b_) * 8192); \
    gload16(ksrc1 + (size_t)(t_) * 8192, kl0 + (b_) * 8192 + 4096); \
    gload16(vsrc0 + (size_t)(t_) * 128,  vl0 + (b_) * 8192); \
    gload16(vsrc1 + (size_t)(t_) * 128,  vl0 + (b_) * 8192 + 4096); \
  } while (0)

  const __bf16* qp = qb + ((size_t)bh * 2048 + q0 + l31) * 64 + h * 8;
  bf16x8 qf[4];
#pragma unroll
  for (int s = 0; s < 4; ++s) qf[s] = *(const bf16x8*)(qp + 16 * s);

  const int swz = (l31 & 7) << 4;
  const int krd = l31 * 128 + ((h * 16) ^ swz);
  const int vrd = 16384 + l31 * 128 + ((h * 16) ^ swz);
  int ka_[8], va_[8];
#pragma unroll
  for (int kvt = 0; kvt < 2; ++kvt)
#pragma unroll
    for (int s = 0; s < 4; ++s) ka_[kvt * 4 + s] = (krd + kvt * 4096) ^ (s * 32);
#pragma unroll
  for (int ks = 0; ks < 4; ++ks)
#pragma unroll
    for (int et = 0; et < 2; ++et) va_[ks * 2 + et] = (vrd + et * 4096) ^ (ks * 32);

  f32x16 FZ;
#pragma unroll
  for (int r = 0; r < 16; ++r) FZ[r] = 0.f;
  bf16x8 onesf;
#pragma unroll
  for (int j = 0; j < 8; ++j) onesf[j] = (__bf16)1.0f;

  f32x16 lacc = FZ;
  f32x16 cacc[2];
  cacc[0] = FZ; cacc[1] = FZ;

  STAGE(0, 0);
  __syncthreads();

#define PKPAIR(dst_, i_)                                                       \
  {                                                                            \
    float pa_ = __builtin_amdgcn_exp2f(sa[2 * (i_)]);                          \
    float pb_ = __builtin_amdgcn_exp2f(sa[2 * (i_) + 1]);                      \
    asm("v_cvt_pk_bf16_f32 %0, %1, %2" : "=v"(dst_) : "v"(pa_), "v"(pb_));     \
  }

#define TILEBODY(B_, T_)                                                       \
  {                                                                            \
    if ((T_) < 31) STAGE((T_) + 1, (B_) ^ 1);                                  \
    bf16x8 kf[2][4], vf[4][2];                                                 \
    _Pragma("unroll") for (int kvt = 0; kvt < 2; ++kvt)                        \
      _Pragma("unroll") for (int s = 0; s < 4; ++s)                            \
        kf[kvt][s] = *(const bf16x8*)(lds + (B_) * 8192 + ka_[kvt * 4 + s]);   \
    _Pragma("unroll") for (int ks = 0; ks < 4; ++ks)                           \
      _Pragma("unroll") for (int et = 0; et < 2; ++et)                         \
        vf[ks][et] = *(const bf16x8*)(lds + (B_) * 8192 + va_[ks * 2 + et]);   \
    u32x4 pau[4];                                                              \
    _Pragma("unroll") for (int kvt = 0; kvt < 2; ++kvt) {                      \
      __builtin_amdgcn_s_setprio(1);                                           \
      f32x16 sa = MFMA32(kf[kvt][0], qf[0], FZ);                               \
      sa = MFMA32(kf[kvt][1], qf[1], sa);                                      \
      sa = MFMA32(kf[kvt][2], qf[2], sa);                                      \
      sa = MFMA32(kf[kvt][3], qf[3], sa);                                      \
      __builtin_amdgcn_s_setprio(0);                                           \
      unsigned c0, c1, c2, c3, c4, c5, c6, c7;                                 \
      PKPAIR(c0, 0) PKPAIR(c1, 1) PKPAIR(c2, 2) PKPAIR(c3, 3)                  \
      PKPAIR(c4, 4) PKPAIR(c5, 5) PKPAIR(c6, 6) PKPAIR(c7, 7)                  \
      asm("v_permlane32_swap_b32 %0, %1" : "+v"(c0), "+v"(c2));                \
      asm("v_permlane32_swap_b32 %0, %1" : "+v"(c1), "+v"(c3));                \
      asm("v_permlane32_swap_b32 %0, %1" : "+v"(c4), "+v"(c6));                \
      asm("v_permlane32_swap_b32 %0, %1" : "+v"(c5), "+v"(c7));                \
      pau[2 * kvt][0] = c0; pau[2 * kvt][1] = c1;                              \
      pau[2 * kvt][2] = c2; pau[2 * kvt][3] = c3;                              \
      pau[2 * kvt + 1][0] = c4; pau[2 * kvt + 1][1] = c5;                      \
      pau[2 * kvt + 1][2] = c6; pau[2 * kvt + 1][3] = c7;                      \
      lacc = MFMA32(__builtin_bit_cast(bf16x8, pau[2 * kvt]), onesf, lacc);    \
      lacc = MFMA32(__builtin_bit_cast(bf16x8, pau[2 * kvt + 1]), onesf, lacc);\
    }                                                                          \
    __builtin_amdgcn_s_setprio(1);                                             \
    _Pragma("unroll") for (int ks = 0; ks < 4; ++ks) {                         \
      bf16x8 paf = __builtin_bit_cast(bf16x8, pau[ks]);                        \
      cacc[0] = MFMA32(paf, vf[ks][0], cacc[0]);                               \
      cacc[1] = MFMA32(paf, vf[ks][1], cacc[1]);                               \
    }                                                                          \
    __builtin_amdgcn_s_setprio(0);                                             \
    __syncthreads();                                                           \
  }

  for (int t = 0; t < 32; t += 2) {
    TILEBODY(0, t)
    TILEBODY(1, t + 1)
  }
#undef TILEBODY
#undef PKPAIR
#undef STAGE

  const int b = bh / 12, hh = bh - b * 12;
#pragma unroll
  for (int r = 0; r < 16; ++r) {
    const int ql = (r & 3) + 8 * (r >> 2) + 4 * h;
    float rl = __builtin_amdgcn_rcpf(lacc[r]);
    size_t base = ((size_t)b * 2048 + q0 + ql) * 768 + hh * 64 + l31;
    ctx[base]      = (__bf16)(cacc[0][r] * rl);
    ctx[base + 32] = (__bf16)(cacc[1][r] * rl);
  }
}

// ---------------- LayerNorm over 768 (one row per block, bf16 h) -------------
__global__ __launch_bounds__(256) void ln_kernel(
    const __bf16* __restrict__ hb, const float* __restrict__ gamma,
    const float* __restrict__ beta, float* __restrict__ out) {
  __shared__ float ssum[4], ssq[4];
  const int row = blockIdx.x, t = threadIdx.x;
  const __bf16* hr = hb + (size_t)row * 768;
  float v0 = (float)hr[t], v1 = (float)hr[t + 256], v2 = (float)hr[t + 512];
  float sum = v0 + v1 + v2;
  float sq = v0 * v0 + v1 * v1 + v2 * v2;
#pragma unroll
  for (int mask = 1; mask < 64; mask <<= 1) {
    sum += __shfl_xor(sum, mask, 64);
    sq += __shfl_xor(sq, mask, 64);
  }
  const int w = t >> 6;
  if ((t & 63) == 0) { ssum[w] = sum; ssq[w] = sq; }
  __syncthreads();
  float s1 = ssum[0] + ssum[1] + ssum[2] + ssum[3];
  float s2 = ssq[0] + ssq[1] + ssq[2] + ssq[3];
  float mu = s1 * (1.0f / 768.0f);
  float var = s2 * (1.0f / 768.0f) - mu * mu;
  float rs = rsqrtf(var + 1e-5f);
  float* orow = out + (size_t)row * 768;
  orow[t]       = (v0 - mu) * rs * gamma[t]       + beta[t];
  orow[t + 256] = (v1 - mu) * rs * gamma[t + 256] + beta[t + 256];
  orow[t + 512] = (v2 - mu) * rs * gamma[t + 512] + beta[t + 512];
}

// ---------------- launch ----------------
extern "C" void kernel_launch(void* const* d_in, const int* in_sizes, int n_in,
                              void* d_out, int out_size, void* d_ws, size_t ws_size,
                              hipStream_t stream) {
  const float* x     = (const float*)d_in[0];
  const float* Wq    = (const float*)d_in[1];
  const float* bq    = (const float*)d_in[2];
  const float* Wk    = (const float*)d_in[3];
  const float* bk    = (const float*)d_in[4];
  const float* Wv    = (const float*)d_in[5];
  const float* bv    = (const float*)d_in[6];
  const float* Wo    = (const float*)d_in[7];
  const float* bo    = (const float*)d_in[8];
  const float* gamma = (const float*)d_in[9];
  const float* beta  = (const float*)d_in[10];
  float* out = (float*)d_out;

  char* ws = (char*)d_ws;
  __bf16* xb   = (__bf16*)(ws);                 // 12582912
  __bf16* wqkv = (__bf16*)(ws + 12582912);      //  3538944
  __bf16* wot  = (__bf16*)(ws + 16121856);      //  1179648
  __bf16* qb   = (__bf16*)(ws + 17301504);      // 12582912
  __bf16* kb   = (__bf16*)(ws + 29884416);      // 12582912
  __bf16* vt   = (__bf16*)(ws + 42467328);      // 12582912
  __bf16* ctx  = (__bf16*)(ws + 55050240);      // 12582912
  __bf16* hb   = (__bf16*)(ws + 67633152);      // 12582912 (bf16)

  pack_kernel<<<dim3(1024), dim3(256), 0, stream>>>(x, Wq, Wk, Wv, Wo, xb, wqkv, wot);
  gemm_qkv<<<dim3(18, 64), dim3(256), 0, stream>>>(xb, wqkv, bq, bk, bv, qb, kb, vt);
  attn_kernel<<<dim3(48, 16), dim3(256), 0, stream>>>(qb, kb, vt, ctx);
  gemm_proj<<<dim3(6, 64), dim3(256), 0, stream>>>(ctx, wot, bo, xb, hb);
  ln_kernel<<<dim3(8192), dim3(256), 0, stream>>>(hb, gamma, beta, out);
}